// Round 4
// baseline (1278.673 us; speedup 1.0000x reference)
//
#include <hip/hip_runtime.h>

#define N_ROWS 4096
#define H_DIM  1024
#define V_SIZE 32000

typedef __bf16 bf16x8 __attribute__((ext_vector_type(8)));
typedef float  f32x4  __attribute__((ext_vector_type(4)));

typedef __attribute__((address_space(1))) void* gas_ptr;
typedef __attribute__((address_space(3))) void* las_ptr;

__device__ __forceinline__ unsigned short f2bf(float f) {
  unsigned u = __float_as_uint(f);
  u += 0x7fffu + ((u >> 16) & 1u);
  return (unsigned short)(u >> 16);
}

__global__ void zero_f32(float* __restrict__ p, int n) {
  int i = blockIdx.x * blockDim.x + threadIdx.x;
  if (i < n) p[i] = 0.0f;
}

// fp32 -> bf16 (RNE), 8 elems/thread, grid-stride
__global__ void cvt_bf16(const float* __restrict__ in, unsigned short* __restrict__ out, int n8) {
  int i = blockIdx.x * blockDim.x + threadIdx.x;
  int stride = gridDim.x * blockDim.x;
  for (; i < n8; i += stride) {
    const float4* p = (const float4*)(in + (size_t)i * 8);
    float4 a = p[0];
    float4 b = p[1];
    uint4 o;
    o.x = (unsigned)f2bf(a.x) | ((unsigned)f2bf(a.y) << 16);
    o.y = (unsigned)f2bf(a.z) | ((unsigned)f2bf(a.w) << 16);
    o.z = (unsigned)f2bf(b.x) | ((unsigned)f2bf(b.y) << 16);
    o.w = (unsigned)f2bf(b.z) | ((unsigned)f2bf(b.w) << 16);
    *(uint4*)(out + (size_t)i * 8) = o;
  }
}

// Bank-conflict swizzle for 64B rows (BK=32 bf16): XOR byte-offset bits 4-5
// with row bits 1-2 (lin bits 7-8). Involution. Fragment read (lanes 0-15 =
// consecutive rows, fixed 16B slot) spreads 8 consecutive rows over all 8
// 16B bank slots -> 2-way max (free per m136).
__device__ __forceinline__ unsigned swz32(unsigned a) {
  return a ^ (((a >> 7) & 3u) << 4);
}

// Fused dual-GEMM + KL partial sums, 2-phase software pipeline.
// grid = 512 blocks (XCD-aware: xcd b&7 gets 4 row-blocks x 16 chunks),
// 256 threads (4 waves, 2x2 of 64x64 per GEMM), BK=32, double-buffered LDS.
// Per row n: Zt = sum exp(t), U = sum exp(t)*(t-s), Zs = sum exp(s).
__global__ __launch_bounds__(256, 1) void fused_kl(
    const unsigned short* __restrict__ xb, const unsigned short* __restrict__ txb,
    const unsigned short* __restrict__ wsb, const unsigned short* __restrict__ wtb,
    float* __restrict__ Zt, float* __restrict__ Uu, float* __restrict__ Zs) {
  // 2 buffers x 4 tiles x 8KB ([128 rows][32 cols] bf16) = 64KB
  __shared__ __align__(16) char smem[65536];

  const unsigned tid = threadIdx.x;
  const unsigned lane = tid & 63u;
  const unsigned w = tid >> 6;           // wave 0..3
  const unsigned wr = w >> 1, wc = w & 1;

  const unsigned b = blockIdx.x;
  const unsigned rb = (b & 7u) * 4u + ((b >> 3) & 3u);  // row-block 0..31
  const unsigned chunk = b >> 5;                        // vocab chunk 0..15
  const unsigned row0 = rb * 128u;
  const unsigned t_begin = chunk * 15u + (chunk < 10u ? chunk : 10u);
  const unsigned t_count = (chunk < 10u) ? 16u : 15u;
  const unsigned NK = t_count * 32u;     // total k-steps (32 per vocab tile)

  // Each wave stages its own tile: w0:x w1:tx w2:Ws w3:Wt
  const unsigned short* gsrc = (w == 0) ? xb : (w == 1) ? txb : (w == 2) ? wsb : wtb;
  const bool a_wave = (w < 2);

  // Per-lane stage geometry: physical LDS = linear (base + lane*16 + i*1KB);
  // global source pre-permuted by the same involution. The XOR key depends
  // only on lane (bits 7-8 of lane*16), so row/byte offsets are i-invariant.
  const unsigned u0 = lane << 4;
  const unsigned q0 = u0 ^ (((u0 >> 7) & 3u) << 4);
  const unsigned r0 = q0 >> 6;        // starting tile row for this lane
  const unsigned byteoff = q0 & 63u;  // byte within row

  float zt1 = 0.f, uu1 = 0.f, zs1 = 0.f;
  const unsigned c = lane & 15u;   // fragment column this lane holds
  const unsigned g = lane >> 4;    // K-quarter / row-group
  const unsigned kb = g << 4;      // byte offset of this lane's 16B within 64B row

  const f32x4 fzero = {0.f, 0.f, 0.f, 0.f};
  f32x4 acc_s[4][4], acc_t[4][4];

  // ---- prologue: stage step 0 into buffer 0 ----
  {
    char* dst = smem + w * 8192u;
    unsigned base_row = a_wave ? row0 : t_begin * 128u;
    const char* s0 = (const char*)gsrc + ((size_t)(base_row + r0) * H_DIM) * 2u + byteoff;
#pragma unroll
    for (unsigned i = 0; i < 8; ++i)
      __builtin_amdgcn_global_load_lds((gas_ptr)(s0 + (size_t)i * (H_DIM * 32u)),
                                       (las_ptr)(dst + i * 1024u), 16, 0, 0);
  }

  for (unsigned t = 0; t < NK; ++t) {
    const unsigned kt = t & 31u;

    // ---- issue next step's staging (other buffer), then counted wait ----
    if (t + 1 < NK) {
      const unsigned tn = t + 1;
      const unsigned k0n = (tn & 31u) * 32u;
      char* dst = smem + ((tn & 1u) * 32768u) + w * 8192u;
      unsigned base_row = a_wave ? row0 : (t_begin + (tn >> 5)) * 128u;
      const char* s0 = (const char*)gsrc + ((size_t)(base_row + r0) * H_DIM + k0n) * 2u + byteoff;
#pragma unroll
      for (unsigned i = 0; i < 8; ++i)
        __builtin_amdgcn_global_load_lds((gas_ptr)(s0 + (size_t)i * (H_DIM * 32u)),
                                         (las_ptr)(dst + i * 1024u), 16, 0, 0);
      // 8 just issued stay in flight; wait only for the previous step's 8
      asm volatile("s_waitcnt vmcnt(8)" ::: "memory");
    } else {
      asm volatile("s_waitcnt vmcnt(0)" ::: "memory");
    }
    __builtin_amdgcn_sched_barrier(0);
    __builtin_amdgcn_s_barrier();   // current buffer fully staged, all waves
    __builtin_amdgcn_sched_barrier(0);

    // ---- compute on buffer t&1 ----
    const char* base = smem + (t & 1u) * 32768u;
    const char* xs  = base;
    const char* ts  = base + 8192;
    const char* wss = base + 16384;
    const char* wts = base + 24576;

    if (kt == 0u) {
#pragma unroll
      for (int mi = 0; mi < 4; ++mi)
#pragma unroll
        for (int ni = 0; ni < 4; ++ni) { acc_s[mi][ni] = fzero; acc_t[mi][ni] = fzero; }
    }

    bf16x8 ax[4], at4[4];
#pragma unroll
    for (int mi = 0; mi < 4; ++mi) {
      unsigned off = swz32((wr * 64u + (unsigned)mi * 16u + c) * 64u + kb);
      ax[mi]  = *(const bf16x8*)(xs + off);
      at4[mi] = *(const bf16x8*)(ts + off);
    }
#pragma unroll
    for (int ni = 0; ni < 4; ++ni) {
      unsigned off = swz32((wc * 64u + (unsigned)ni * 16u + c) * 64u + kb);
      bf16x8 bs = *(const bf16x8*)(wss + off);
      bf16x8 bt = *(const bf16x8*)(wts + off);
#pragma unroll
      for (int mi = 0; mi < 4; ++mi) {
        acc_s[mi][ni] = __builtin_amdgcn_mfma_f32_16x16x32_bf16(ax[mi],  bs, acc_s[mi][ni], 0, 0, 0);
        acc_t[mi][ni] = __builtin_amdgcn_mfma_f32_16x16x32_bf16(at4[mi], bt, acc_t[mi][ni], 0, 0, 0);
      }
    }

    // ---- per-vocab-tile epilogue: fold logits into per-lane KL sums ----
    if (kt == 31u) {
      // C/D layout: col = lane&15, row = (lane>>4)*4 + j (m89-verified)
#pragma unroll
      for (int mi = 0; mi < 4; ++mi)
#pragma unroll
        for (int j = 0; j < 4; ++j) {
          float ztl = 0.f, uul = 0.f, zsl = 0.f;
#pragma unroll
          for (int ni = 0; ni < 4; ++ni) {
            float s = acc_s[mi][ni][j];
            float tt = acc_t[mi][ni][j];
            float et = __expf(tt);
            ztl += et;
            uul += et * (tt - s);
            zsl += __expf(s);
          }
          ztl += __shfl_xor(ztl, 1); ztl += __shfl_xor(ztl, 2);
          ztl += __shfl_xor(ztl, 4); ztl += __shfl_xor(ztl, 8);
          uul += __shfl_xor(uul, 1); uul += __shfl_xor(uul, 2);
          uul += __shfl_xor(uul, 4); uul += __shfl_xor(uul, 8);
          zsl += __shfl_xor(zsl, 1); zsl += __shfl_xor(zsl, 2);
          zsl += __shfl_xor(zsl, 4); zsl += __shfl_xor(zsl, 8);
          if (c == (unsigned)(mi * 4 + j)) { zt1 += ztl; uu1 += uul; zs1 += zsl; }
        }
    }

    __builtin_amdgcn_s_barrier();   // all reads of buffer t&1 done before overwrite
  }

  // Lane (g,c) owns row: wr*64 + (c>>2)*16 + g*4 + (c&3)  (bijective over 64 rows)
  {
    unsigned n = row0 + wr * 64u + (c >> 2) * 16u + g * 4u + (c & 3u);
    atomicAdd(&Zt[n], zt1);
    atomicAdd(&Uu[n], uu1);
    atomicAdd(&Zs[n], zs1);
  }
}

// KL_n = U/Zt - log Zt + log Zs ; out = mean over N, float32.
__global__ void finalize_kl(const float* __restrict__ Zt, const float* __restrict__ Uu,
                            const float* __restrict__ Zs, float* __restrict__ out) {
  __shared__ float red[4];
  float s = 0.f;
  for (int r = threadIdx.x; r < N_ROWS; r += 256) {
    s += Uu[r] / Zt[r] - __logf(Zt[r]) + __logf(Zs[r]);
  }
  s += __shfl_xor(s, 1); s += __shfl_xor(s, 2); s += __shfl_xor(s, 4);
  s += __shfl_xor(s, 8); s += __shfl_xor(s, 16); s += __shfl_xor(s, 32);
  if ((threadIdx.x & 63) == 0) red[threadIdx.x >> 6] = s;
  __syncthreads();
  if (threadIdx.x == 0) {
    float tot = red[0] + red[1] + red[2] + red[3];
    out[0] = tot / (float)N_ROWS;
  }
}

extern "C" void kernel_launch(void* const* d_in, const int* in_sizes, int n_in,
                              void* d_out, int out_size, void* d_ws, size_t ws_size,
                              hipStream_t stream) {
  const float* x  = (const float*)d_in[0];
  const float* tx = (const float*)d_in[1];
  const float* Ws = (const float*)d_in[2];
  const float* Wt = (const float*)d_in[3];

  char* ws = (char*)d_ws;
  float* Zt = (float*)ws;
  float* Uu = Zt + N_ROWS;
  float* Zs = Uu + N_ROWS;
  unsigned short* xb  = (unsigned short*)(ws + 65536);
  unsigned short* txb = xb  + (size_t)N_ROWS * H_DIM;
  unsigned short* wsb = txb + (size_t)N_ROWS * H_DIM;
  unsigned short* wtb = wsb + (size_t)V_SIZE * H_DIM;

  zero_f32<<<(3 * N_ROWS) / 256, 256, 0, stream>>>(Zt, 3 * N_ROWS);
  cvt_bf16<<<2048, 256, 0, stream>>>(x,  xb,  (N_ROWS * H_DIM) / 8);
  cvt_bf16<<<2048, 256, 0, stream>>>(tx, txb, (N_ROWS * H_DIM) / 8);
  cvt_bf16<<<4096, 256, 0, stream>>>(Ws, wsb, (V_SIZE * H_DIM) / 8);
  cvt_bf16<<<4096, 256, 0, stream>>>(Wt, wtb, (V_SIZE * H_DIM) / 8);
  fused_kl<<<512, 256, 0, stream>>>(xb, txb, wsb, wtb, Zt, Uu, Zs);
  finalize_kl<<<1, 256, 0, stream>>>(Zt, Uu, Zs, (float*)d_out);
}

// Round 5
// 575.474 us; speedup vs baseline: 2.2219x; 2.2219x over previous
//
#include <hip/hip_runtime.h>
#include <hip/hip_fp8.h>

#define N_ROWS 4096
#define H_DIM  1024
#define V_SIZE 32000

typedef float f32x4 __attribute__((ext_vector_type(4)));

typedef __attribute__((address_space(1))) void* gas_ptr;
typedef __attribute__((address_space(3))) void* las_ptr;

__global__ void zero_f32(float* __restrict__ p, int n) {
  int i = blockIdx.x * blockDim.x + threadIdx.x;
  if (i < n) p[i] = 0.0f;
}

__device__ __forceinline__ unsigned pk4_fp8(float a, float b, float c, float d) {
#if __has_builtin(__builtin_amdgcn_cvt_pk_fp8_f32)
  int v = __builtin_amdgcn_cvt_pk_fp8_f32(a, b, 0, false);
  v = __builtin_amdgcn_cvt_pk_fp8_f32(c, d, v, true);
  return (unsigned)v;
#else
  __hip_fp8_e4m3 qa(a), qb(b), qc(c), qd(d);
  return (unsigned)qa.__x | ((unsigned)qb.__x << 8) | ((unsigned)qc.__x << 16) |
         ((unsigned)qd.__x << 24);
#endif
}

// fp32 -> fp8 e4m3, with the LDS bank swizzle PRE-BAKED into the HBM layout:
// out[row*1024 + (k ^ ((row&7)<<3))] = fp8(in[row*1024 + k]).
// The XOR key is < 64, so it permutes within each 64B K-block; later the GEMM
// stages 64B-per-row tiles LINEARLY via global_load_lds and applies the same
// XOR on ds_read (rule 21: same involution on both sides).
__global__ void cvt_fp8(const float* __restrict__ in, unsigned char* __restrict__ out, int total16) {
  int idx = blockIdx.x * blockDim.x + threadIdx.x;
  int stride = gridDim.x * blockDim.x;
  for (; idx < total16; idx += stride) {
    unsigned row = (unsigned)idx >> 6;          // H_DIM/16 = 64 chunks per row
    unsigned k0 = ((unsigned)idx & 63u) << 4;
    const float4* p = (const float4*)(in + (size_t)row * H_DIM + k0);
    float4 f0 = p[0], f1 = p[1], f2 = p[2], f3 = p[3];
    unsigned long long u0 = (unsigned long long)pk4_fp8(f0.x, f0.y, f0.z, f0.w) |
                            ((unsigned long long)pk4_fp8(f1.x, f1.y, f1.z, f1.w) << 32);
    unsigned long long u1 = (unsigned long long)pk4_fp8(f2.x, f2.y, f2.z, f2.w) |
                            ((unsigned long long)pk4_fp8(f3.x, f3.y, f3.z, f3.w) << 32);
    unsigned key = (row & 7u) << 3;
    unsigned char* ob = out + (size_t)row * H_DIM;
    *(unsigned long long*)(ob + (k0 ^ key)) = u0;
    *(unsigned long long*)(ob + ((k0 + 8u) ^ key)) = u1;
  }
}

// Fused dual-GEMM (fp8 e4m3 MFMA) + KL partial sums.
// grid = 512 (XCD-aware), 256 threads (4 waves, 2x2 of 64x64), BK=64.
// LDS: 4 tiles x [128 rows][64B] = 32KB, single-buffered, bulk-sync.
// Per row n: Zt = sum exp(t), U = sum exp(t)*(t-s), Zs = sum exp(s).
__global__ __launch_bounds__(256, 2) void fused_kl(
    const unsigned char* __restrict__ x8, const unsigned char* __restrict__ tx8,
    const unsigned char* __restrict__ ws8, const unsigned char* __restrict__ wt8,
    float* __restrict__ Zt, float* __restrict__ Uu, float* __restrict__ Zs) {
  __shared__ __align__(16) char smem[32768];  // xs | ts | wss | wts (8KB each)

  const unsigned tid = threadIdx.x;
  const unsigned lane = tid & 63u;
  const unsigned w = tid >> 6;
  const unsigned wr = w >> 1, wc = w & 1;

  const unsigned b = blockIdx.x;
  const unsigned rb = (b & 7u) * 4u + ((b >> 3) & 3u);  // row-block 0..31
  const unsigned chunk = b >> 5;                        // vocab chunk 0..15
  const unsigned row0 = rb * 128u;
  const unsigned t_begin = chunk * 15u + (chunk < 10u ? chunk : 10u);
  const unsigned t_count = (chunk < 10u) ? 16u : 15u;

  const unsigned c = lane & 15u;   // fragment column/row index within 16
  const unsigned g = lane >> 4;    // k-group (8 fp8 each)
  const unsigned keyc = (c & 7u) << 3;

  // ds_read base addresses (constant across ALL k-steps; tiles are reused).
  // A-side byte: wr*4096 + mi*1024 + c*64 + ((kk*32 + g*8) ^ keyc)   [+8192 for ts]
  // B-side byte: 16384 + wc*4096 + ni*1024 + c*64 + ((kk*32+g*8)^keyc) [+8192 for wts]
  const unsigned fragoff0 = ((g << 3)) ^ keyc;          // kk = 0
  const unsigned fragoff1 = (32u + (g << 3)) ^ keyc;    // kk = 1
  const char* baseA0 = smem + wr * 4096u + c * 64u + fragoff0;
  const char* baseA1 = smem + wr * 4096u + c * 64u + fragoff1;
  const char* baseB0 = smem + 16384u + wc * 4096u + c * 64u + fragoff0;
  const char* baseB1 = smem + 16384u + wc * 4096u + c * 64u + fragoff1;

  // Staging: wave w stages tile w (8KB): 8 x global_load_lds(16B) per lane.
  // LDS dest linear; source is the pre-swizzled fp8 array, read linearly.
  char* stage_dst = smem + w * 8192u + lane * 16u;
  const unsigned srow = lane >> 2;          // +i*16 per load
  const unsigned sbyte = (lane & 3u) * 16u;
  const unsigned char* gsrc = (w == 0) ? x8 : (w == 1) ? tx8 : (w == 2) ? ws8 : wt8;
  const bool a_wave = (w < 2);

  float zt1 = 0.f, uu1 = 0.f, zs1 = 0.f;
  const f32x4 fzero = {0.f, 0.f, 0.f, 0.f};

  for (unsigned vt = 0; vt < t_count; ++vt) {
    const unsigned tile_row0 = a_wave ? row0 : (t_begin + vt) * 128u;
    const unsigned char* src_base = gsrc + (size_t)(tile_row0 + srow) * H_DIM + sbyte;
    f32x4 acc_s[4][4], acc_t[4][4];
#pragma unroll
    for (int mi = 0; mi < 4; ++mi)
#pragma unroll
      for (int ni = 0; ni < 4; ++ni) { acc_s[mi][ni] = fzero; acc_t[mi][ni] = fzero; }

    for (unsigned kt = 0; kt < 16; ++kt) {
      __syncthreads();  // previous step's ds_reads done before overwrite
      {
        const unsigned char* s0 = src_base + kt * 64u;
#pragma unroll
        for (unsigned i = 0; i < 8; ++i)
          __builtin_amdgcn_global_load_lds((gas_ptr)(s0 + (size_t)i * (16u * H_DIM)),
                                           (las_ptr)(stage_dst + i * 1024u), 16, 0, 0);
      }
      __syncthreads();  // drains vmcnt(0) before s_barrier -> staging visible

#pragma unroll
      for (int kk = 0; kk < 2; ++kk) {
        const char* bA = kk ? baseA1 : baseA0;
        const char* bB = kk ? baseB1 : baseB0;
        long long ax[4], at4[4];
#pragma unroll
        for (int mi = 0; mi < 4; ++mi) {
          ax[mi]  = *(const long long*)(bA + mi * 1024);
          at4[mi] = *(const long long*)(bA + mi * 1024 + 8192);
        }
#pragma unroll
        for (int ni = 0; ni < 4; ++ni) {
          long long bs = *(const long long*)(bB + ni * 1024);
          long long bt = *(const long long*)(bB + ni * 1024 + 8192);
#pragma unroll
          for (int mi = 0; mi < 4; ++mi) {
            acc_s[mi][ni] = __builtin_amdgcn_mfma_f32_16x16x32_fp8_fp8(ax[mi],  bs, acc_s[mi][ni], 0, 0, 0);
            acc_t[mi][ni] = __builtin_amdgcn_mfma_f32_16x16x32_fp8_fp8(at4[mi], bt, acc_t[mi][ni], 0, 0, 0);
          }
        }
      }
    }

    // Epilogue: fold this 128-col logit tile into per-lane KL sums.
    // C/D layout: col = lane&15, row = (lane>>4)*4 + j (m89-verified)
#pragma unroll
    for (int mi = 0; mi < 4; ++mi)
#pragma unroll
      for (int j = 0; j < 4; ++j) {
        float ztl = 0.f, uul = 0.f, zsl = 0.f;
#pragma unroll
        for (int ni = 0; ni < 4; ++ni) {
          float s = acc_s[mi][ni][j];
          float tt = acc_t[mi][ni][j];
          float et = __expf(tt);
          ztl += et;
          uul += et * (tt - s);
          zsl += __expf(s);
        }
        ztl += __shfl_xor(ztl, 1); ztl += __shfl_xor(ztl, 2);
        ztl += __shfl_xor(ztl, 4); ztl += __shfl_xor(ztl, 8);
        uul += __shfl_xor(uul, 1); uul += __shfl_xor(uul, 2);
        uul += __shfl_xor(uul, 4); uul += __shfl_xor(uul, 8);
        zsl += __shfl_xor(zsl, 1); zsl += __shfl_xor(zsl, 2);
        zsl += __shfl_xor(zsl, 4); zsl += __shfl_xor(zsl, 8);
        if (c == (unsigned)(mi * 4 + j)) { zt1 += ztl; uu1 += uul; zs1 += zsl; }
      }
  }

  // Lane (g,c) owns row: wr*64 + (c>>2)*16 + g*4 + (c&3)  (bijective over 64 rows)
  {
    unsigned n = row0 + wr * 64u + (c >> 2) * 16u + g * 4u + (c & 3u);
    atomicAdd(&Zt[n], zt1);
    atomicAdd(&Uu[n], uu1);
    atomicAdd(&Zs[n], zs1);
  }
}

// KL_n = U/Zt - log Zt + log Zs ; out = mean over N, float32.
__global__ void finalize_kl(const float* __restrict__ Zt, const float* __restrict__ Uu,
                            const float* __restrict__ Zs, float* __restrict__ out) {
  __shared__ float red[4];
  float s = 0.f;
  for (int r = threadIdx.x; r < N_ROWS; r += 256) {
    s += Uu[r] / Zt[r] - __logf(Zt[r]) + __logf(Zs[r]);
  }
  s += __shfl_xor(s, 1); s += __shfl_xor(s, 2); s += __shfl_xor(s, 4);
  s += __shfl_xor(s, 8); s += __shfl_xor(s, 16); s += __shfl_xor(s, 32);
  if ((threadIdx.x & 63) == 0) red[threadIdx.x >> 6] = s;
  __syncthreads();
  if (threadIdx.x == 0) {
    float tot = red[0] + red[1] + red[2] + red[3];
    out[0] = tot / (float)N_ROWS;
  }
}

extern "C" void kernel_launch(void* const* d_in, const int* in_sizes, int n_in,
                              void* d_out, int out_size, void* d_ws, size_t ws_size,
                              hipStream_t stream) {
  const float* x  = (const float*)d_in[0];
  const float* tx = (const float*)d_in[1];
  const float* Ws = (const float*)d_in[2];
  const float* Wt = (const float*)d_in[3];

  char* ws = (char*)d_ws;
  float* Zt = (float*)ws;
  float* Uu = Zt + N_ROWS;
  float* Zs = Uu + N_ROWS;
  unsigned char* x8  = (unsigned char*)(ws + 65536);
  unsigned char* tx8 = x8  + (size_t)N_ROWS * H_DIM;
  unsigned char* ws8 = tx8 + (size_t)N_ROWS * H_DIM;
  unsigned char* wt8 = ws8 + (size_t)V_SIZE * H_DIM;

  zero_f32<<<(3 * N_ROWS) / 256, 256, 0, stream>>>(Zt, 3 * N_ROWS);
  cvt_fp8<<<1024, 256, 0, stream>>>(x,  x8,  N_ROWS * (H_DIM / 16));
  cvt_fp8<<<1024, 256, 0, stream>>>(tx, tx8, N_ROWS * (H_DIM / 16));
  cvt_fp8<<<2048, 256, 0, stream>>>(Ws, ws8, V_SIZE * (H_DIM / 16));
  cvt_fp8<<<2048, 256, 0, stream>>>(Wt, wt8, V_SIZE * (H_DIM / 16));
  fused_kl<<<512, 256, 0, stream>>>(x8, tx8, ws8, wt8, Zt, Uu, Zs);
  finalize_kl<<<1, 256, 0, stream>>>(Zt, Uu, Zs, (float*)d_out);
}